// Round 3
// baseline (467.486 us; speedup 1.0000x reference)
//
#include <hip/hip_runtime.h>

#define LOG2E 1.44269504088896340736f

typedef __attribute__((ext_vector_type(8))) _Float16 half8;
typedef __attribute__((ext_vector_type(4))) float floatx4;

// ---------------------------------------------------------------------------
// Single fused kernel — no prep dispatch, no workspace.
//
// Wave-local barrier-free pipeline: wave w computes h for its own 64 nodes,
// stages h as f16 in its own LDS slice (XOR-chunk swizzled), waits
// lgkmcnt(0) (wave-local handoff — no __syncthreads), then MFMAs.
//
// W1 symmetric-pair folding is done inline in phase 1 (uniform-index scalar
// loads from the 1 KB W1 table, constant-cache-hot; the pair-add is SALU).
//
// W2's split-precision f16 hi/lo fragments are built IN REGISTERS inside
// phase 2, per channel-group c, straight from the f32 W2 table (16 KB,
// L1-resident after the first wave). Identical hi/lo arithmetic to the old
// prep kernel -> bit-identical numerics. Fragments live only one c-iteration,
// cutting peak VGPR so __launch_bounds__(256,5) gives 5 blocks/CU
// (LDS 32 KB x 5 = 160 KB exactly), 20 waves/CU for latency hiding.
//
// Phase 2 uses OPERAND-SWAPPED MFMA: mfma(W2frag, hfrag) computes the
// transposed tile D[channel][node]; lane&15 -> the lane's own node,
// q*4+reg -> 4 consecutive channels -> one float4 store per (c,s), with
// each store instruction covering 16 fully-written 64 B lines.
// (Plain stores: nontemporal measured -15 us regression in round 1.)
// ---------------------------------------------------------------------------
__global__ __launch_bounds__(256, 5) void vnmlp_mfma(
    const float* __restrict__ node_pos,   // [N,3]
    const float* __restrict__ vn_pos,     // [G,12]
    const void*  __restrict__ batch_raw,  // [N] int32 or int64 (probed)
    const float* __restrict__ W1,         // [64,16]
    const float* __restrict__ b1,         // [64]
    const float* __restrict__ W2,         // [64,64]
    const float* __restrict__ b2,         // [64]
    float*       __restrict__ out,        // [N,64]
    int n)
{
    __shared__ _Float16 lds_h[256 * 64];  // 32 KB

    const int t    = threadIdx.x;
    const int base = blockIdx.x * 256;
    const int i    = base + t;
    const int ic   = (i < n) ? i : (n - 1);   // clamped: loads always safe
    const bool full = (base + 256 <= n);      // block-uniform

    const int l  = t & 63;
    const int w  = t >> 6;
    const int lm = l & 15;   // node index within 16-tile
    const int q  = l >> 4;   // quarter-wave

    // ---- Phase 1: per-node h (uniform, no divergence; ic-clamped) ----
    // batch dtype probe (int32 vs int64), wave-uniform
    const int* b32 = (const int*)batch_raw;
    const int probe = b32[(n / 2) | 1] | b32[(n / 4) | 1] | b32[((n / 4) * 3) | 1];
    long long bi;
    if (probe == 0) bi = ((const long long*)batch_raw)[ic];
    else            bi = (long long)b32[ic];

    const float px = node_pos[3 * ic + 0];
    const float py = node_pos[3 * ic + 1];
    const float pz = node_pos[3 * ic + 2];

    // vn_pos row: 48 B, 16 B-aligned (48*bi % 16 == 0) -> 3x float4
    const float4* vp4 = (const float4*)(vn_pos + 12 * bi);
    const float4 v0 = vp4[0], v1 = vp4[1], v2 = vp4[2];
    const float vx[4] = {px - v0.x, px - v0.w, px - v1.z, px - v2.y};
    const float vy[4] = {py - v0.y, py - v1.x, py - v1.w, py - v2.z};
    const float vz[4] = {pz - v0.z, pz - v1.y, pz - v2.x, pz - v2.w};

    float dn[6];
    float ss = 0.0f;
    {
        int p = 0;
#pragma unroll
        for (int a = 0; a < 4; ++a) {
#pragma unroll
            for (int k = a + 1; k < 4; ++k) {
                const float dx = vx[a] - vx[k];
                const float dy = vy[a] - vy[k];
                const float dz = vz[a] - vz[k];
                const float sq = dx * dx + dy * dy + dz * dz;
                dn[p++] = __builtin_amdgcn_sqrtf(sq);
                ss += sq;
            }
        }
    }
    ss *= 2.0f;  // each unique pair appears twice in the 16-vector
    const float inv = __builtin_amdgcn_rcpf(__builtin_amdgcn_sqrtf(ss) + 0.001f);
#pragma unroll
    for (int p = 0; p < 6; ++p) dn[p] *= inv;

    // h produced in chunks of 8 -> silu -> f16 -> LDS (low live-register).
    // W1 pair-fold inline: uniform compile-time indices -> scalar loads.
    // LDS XOR-chunk swizzle: chunk c of node t at chunk index c ^ (t&7).
    const int pa[6] = {0, 0, 0, 1, 1, 2};
    const int pb[6] = {1, 2, 3, 2, 3, 3};
#pragma unroll
    for (int c = 0; c < 8; ++c) {
        half8 v;
#pragma unroll
        for (int jj = 0; jj < 8; ++jj) {
            const int j = c * 8 + jj;
            float acc = b1[j];
#pragma unroll
            for (int p = 0; p < 6; ++p) {
                const float we = W1[j * 16 + pa[p] * 4 + pb[p]] + W1[j * 16 + pb[p] * 4 + pa[p]];
                acc = fmaf(dn[p], we, acc);
            }
            const float e = __builtin_amdgcn_exp2f(-LOG2E * acc);
            v[jj] = (_Float16)(acc * __builtin_amdgcn_rcpf(1.0f + e));
        }
        *(half8*)&lds_h[t * 64 + ((c ^ (t & 7)) * 8)] = v;
    }

    // Wave-local handoff: our MFMA rows were written by our own lanes.
    __asm__ volatile("s_waitcnt lgkmcnt(0)" ::: "memory");

    // ---- Phase 2: per-wave MFMA, wave w owns nodes [w*64, w*64+64) ----
    // Load all A-fragments (this wave's own h rows) once: 8 ds_read_b128.
    half8 Ah[4][2];
#pragma unroll
    for (int s = 0; s < 4; ++s) {
        const int nn = w * 64 + s * 16 + lm;
#pragma unroll
        for (int ks = 0; ks < 2; ++ks) {
            const int kc = ks * 4 + q;
            Ah[s][ks] = *(const half8*)&lds_h[nn * 64 + ((kc ^ (nn & 7)) * 8)];
        }
    }

#pragma unroll 1
    for (int c = 0; c < 4; ++c) {
        // Build W2 hi/lo fragments for channel group c in registers.
        // frag element j of (ks): W2[(c*16+lm)*64 + ks*32 + q*8 + j]
        half8 Bh[2], Bl[2];
#pragma unroll
        for (int ks = 0; ks < 2; ++ks) {
            const float* wrow = W2 + (c * 16 + lm) * 64 + ks * 32 + q * 8;
            const floatx4 f0 = *(const floatx4*)(wrow);
            const floatx4 f1 = *(const floatx4*)(wrow + 4);
#pragma unroll
            for (int e = 0; e < 4; ++e) {
                const _Float16 h0 = (_Float16)f0[e];
                Bh[ks][e] = h0;
                Bl[ks][e] = (_Float16)(f0[e] - (float)h0);
                const _Float16 h1 = (_Float16)f1[e];
                Bh[ks][4 + e] = h1;
                Bl[ks][4 + e] = (_Float16)(f1[e] - (float)h1);
            }
        }
        // swapped layout: lane holds channels c*16 + q*4 .. +3 (row dim)
        const floatx4 bv = *(const floatx4*)(b2 + c * 16 + q * 4);

#pragma unroll
        for (int s = 0; s < 4; ++s) {
            floatx4 acc = bv;
#pragma unroll
            for (int ks = 0; ks < 2; ++ks) {
                acc = __builtin_amdgcn_mfma_f32_16x16x32_f16(Bh[ks], Ah[s][ks], acc, 0, 0, 0);
                acc = __builtin_amdgcn_mfma_f32_16x16x32_f16(Bl[ks], Ah[s][ks], acc, 0, 0, 0);
            }
            const int node = base + w * 64 + s * 16 + lm;  // lane's output row
            if (full || node < n)
                *(floatx4*)(out + (size_t)node * 64 + c * 16 + q * 4) = acc;
        }
    }
}

extern "C" void kernel_launch(void* const* d_in, const int* in_sizes, int n_in,
                              void* d_out, int out_size, void* d_ws, size_t ws_size,
                              hipStream_t stream) {
    // setup_inputs order: node_feat(0, unused), node_pos(1), vn_pos(2),
    // batch(3), W1(4), b1(5), W2(6), b2(7)
    const float* node_pos = (const float*)d_in[1];
    const float* vn_pos   = (const float*)d_in[2];
    const void*  batch    = d_in[3];
    const float* W1       = (const float*)d_in[4];
    const float* b1       = (const float*)d_in[5];
    const float* W2       = (const float*)d_in[6];
    const float* b2       = (const float*)d_in[7];
    float* out = (float*)d_out;

    const int n = in_sizes[1] / 3;
    const int blocks = (n + 255) / 256;

    hipLaunchKernelGGL(vnmlp_mfma, dim3(blocks), dim3(256), 0, stream,
                       node_pos, vn_pos, batch, W1, b1, W2, b2, out, n);
}